// Round 10
// baseline (224.841 us; speedup 1.0000x reference)
//
#include <hip/hip_runtime.h>
#include <cstdint>
#include <cstddef>

#define SEQL   2048
#define DMODEL 1024
#define NHEADS 16
#define DHEAD  64
#define MROWS  4096   // BATCH * SEQ

typedef __attribute__((ext_vector_type(8))) short short8;   // 8 bf16 (4 VGPRs)
typedef __attribute__((ext_vector_type(4))) float f32x4;    // MFMA 16x16 C/D

__device__ __forceinline__ unsigned short f2bf(float x) {
  unsigned int u = __float_as_uint(x);
  u += 0x7fffu + ((u >> 16) & 1u);   // round-to-nearest-even
  return (unsigned short)(u >> 16);
}
__device__ __forceinline__ float bf2f(unsigned short u) {
  return __uint_as_float(((unsigned int)u) << 16);
}
// load 8 contiguous fp32, round to 8 bf16
__device__ __forceinline__ short8 cvt8(const float* __restrict__ p) {
  const float4 lo = *(const float4*)p;
  const float4 hi = *(const float4*)(p + 4);
  short8 v;
  v[0] = (short)f2bf(lo.x); v[1] = (short)f2bf(lo.y);
  v[2] = (short)f2bf(lo.z); v[3] = (short)f2bf(lo.w);
  v[4] = (short)f2bf(hi.x); v[5] = (short)f2bf(hi.y);
  v[6] = (short)f2bf(hi.z); v[7] = (short)f2bf(hi.w);
  return v;
}
// async global->LDS, 16B per lane; lds base must be wave-uniform
__device__ __forceinline__ void gload_lds16(const unsigned short* g, unsigned short* l) {
  __builtin_amdgcn_global_load_lds(
      (const __attribute__((address_space(1))) unsigned int*)g,
      (__attribute__((address_space(3))) unsigned int*)l, 16, 0, 0);
}

// ---------------------------------------------------------------------------
// One-shot fp32 -> bf16 conversion of x and the four weight matrices.
// ---------------------------------------------------------------------------
__global__ __launch_bounds__(256) void cvt_bf16(
    const float* __restrict__ x,  const float* __restrict__ wq,
    const float* __restrict__ wk, const float* __restrict__ wv,
    const float* __restrict__ wo,
    unsigned short* __restrict__ xb,  unsigned short* __restrict__ wqb,
    unsigned short* __restrict__ wkb, unsigned short* __restrict__ wvb,
    unsigned short* __restrict__ wob) {
  const int y = blockIdx.y;
  const float* src; unsigned short* dst;
  if (y < 4)       { src = x + ((size_t)y << 20); dst = xb + ((size_t)y << 20); }
  else if (y == 4) { src = wq; dst = wqb; }
  else if (y == 5) { src = wk; dst = wkb; }
  else if (y == 6) { src = wv; dst = wvb; }
  else             { src = wo; dst = wob; }
  const size_t i = ((size_t)blockIdx.x * 256 + threadIdx.x) * 8;
  *(short8*)(dst + i) = cvt8(src + i);
}

// ---------------------------------------------------------------------------
// QKV projection, all-bf16, async staging (m97-style).
// z=0 -> Q bf16; z=1 -> K bf16; z=2 -> V transposed into Vt.
// ---------------------------------------------------------------------------
__global__ __launch_bounds__(256) void gemm_qkv(
    const unsigned short* __restrict__ A,
    const unsigned short* __restrict__ W0, const unsigned short* __restrict__ W1,
    const unsigned short* __restrict__ W2,
    unsigned short* __restrict__ C0, unsigned short* __restrict__ C1,
    unsigned short* __restrict__ Vt,
    int Mda, int Nda, int Kda) {
  const unsigned short* W;
  if (blockIdx.z == 0)      W = W0;
  else if (blockIdx.z == 1) W = W1;
  else                      W = W2;

  __shared__ __attribute__((aligned(16))) unsigned short As[128 * 32];
  __shared__ __attribute__((aligned(16))) unsigned short Bs[128 * 32];

  const int t = threadIdx.x;
  const int m0 = blockIdx.y * 128, n0 = blockIdx.x * 128;
  const int w = t >> 6, lane = t & 63;
  const int l15 = lane & 15, quad = lane >> 4;
  const int wm = (w >> 1) * 64, wn = (w & 1) * 64;

  const int r1 = t >> 2,         c1 = (t & 3) * 8;
  const int r2 = (t + 256) >> 2, c2 = (t & 3) * 8;
  unsigned short* asd1 = As + (size_t)(w << 6) * 8;
  unsigned short* asd2 = As + (size_t)(256 + (w << 6)) * 8;
  unsigned short* bsd1 = Bs + (size_t)(w << 6) * 8;
  unsigned short* bsd2 = Bs + (size_t)(256 + (w << 6)) * 8;

  f32x4 acc[4][4] = {};

  for (int k0 = 0; k0 < Kda; k0 += 32) {
    __syncthreads();
    gload_lds16(A + (size_t)(m0 + r1) * Kda + k0 + c1, asd1);
    gload_lds16(A + (size_t)(m0 + r2) * Kda + k0 + c2, asd2);
    gload_lds16(W + (size_t)(n0 + r1) * Kda + k0 + c1, bsd1);
    gload_lds16(W + (size_t)(n0 + r2) * Kda + k0 + c2, bsd2);
    __syncthreads();

    short8 af[4], bfr[4];
#pragma unroll
    for (int i = 0; i < 4; ++i)
      af[i] = *(const short8*)(&As[(wm + i * 16 + l15) * 32 + quad * 8]);
#pragma unroll
    for (int j = 0; j < 4; ++j)
      bfr[j] = *(const short8*)(&Bs[(wn + j * 16 + l15) * 32 + quad * 8]);
#pragma unroll
    for (int i = 0; i < 4; ++i)
#pragma unroll
      for (int j = 0; j < 4; ++j)
        acc[i][j] = __builtin_amdgcn_mfma_f32_16x16x32_bf16(af[i], bfr[j], acc[i][j], 0, 0, 0);
  }

  if (blockIdx.z != 2) {
    unsigned short* C = (blockIdx.z == 0) ? C0 : C1;
#pragma unroll
    for (int i = 0; i < 4; ++i)
#pragma unroll
      for (int j = 0; j < 4; ++j)
#pragma unroll
        for (int r = 0; r < 4; ++r) {
          int row = m0 + wm + i * 16 + quad * 4 + r;
          int col = n0 + wn + j * 16 + l15;
          C[(size_t)row * Nda + col] = f2bf(acc[i][j][r]);
        }
  } else {
    // V transposed write: 4 consecutive s-values per 8B store
#pragma unroll
    for (int i = 0; i < 4; ++i) {
      const int srow = m0 + wm + i * 16 + quad * 4;   // b*SEQL + s (s%4==0)
      const int bq = srow >> 11, s = srow & (SEQL - 1);
#pragma unroll
      for (int j = 0; j < 4; ++j) {
        const int col = n0 + wn + j * 16 + l15;       // h*64 + d
        ushort4 v;
        v.x = f2bf(acc[i][j][0]); v.y = f2bf(acc[i][j][1]);
        v.z = f2bf(acc[i][j][2]); v.w = f2bf(acc[i][j][3]);
        *(ushort4*)(Vt + ((size_t)(bq * DMODEL + col)) * SEQL + s) = v;
      }
    }
  }
}

// ---------------------------------------------------------------------------
// Output projection: A bf16 [M][K], W bf16 [N][K], C fp32 [M][N]
// ---------------------------------------------------------------------------
__global__ __launch_bounds__(256) void gemm_out(
    const unsigned short* __restrict__ A,
    const unsigned short* __restrict__ W,
    float* __restrict__ C,
    int Mda, int Nda, int Kda) {
  __shared__ __attribute__((aligned(16))) unsigned short As[128 * 32];
  __shared__ __attribute__((aligned(16))) unsigned short Bs[128 * 32];

  const int t = threadIdx.x;
  const int m0 = blockIdx.y * 128, n0 = blockIdx.x * 128;
  const int w = t >> 6, lane = t & 63;
  const int l15 = lane & 15, quad = lane >> 4;
  const int wm = (w >> 1) * 64, wn = (w & 1) * 64;

  const int r1 = t >> 2,         c1 = (t & 3) * 8;
  const int r2 = (t + 256) >> 2, c2 = (t & 3) * 8;
  unsigned short* asd1 = As + (size_t)(w << 6) * 8;
  unsigned short* asd2 = As + (size_t)(256 + (w << 6)) * 8;
  unsigned short* bsd1 = Bs + (size_t)(w << 6) * 8;
  unsigned short* bsd2 = Bs + (size_t)(256 + (w << 6)) * 8;

  f32x4 acc[4][4] = {};

  for (int k0 = 0; k0 < Kda; k0 += 32) {
    __syncthreads();
    gload_lds16(A + (size_t)(m0 + r1) * Kda + k0 + c1, asd1);
    gload_lds16(A + (size_t)(m0 + r2) * Kda + k0 + c2, asd2);
    gload_lds16(W + (size_t)(n0 + r1) * Kda + k0 + c1, bsd1);
    gload_lds16(W + (size_t)(n0 + r2) * Kda + k0 + c2, bsd2);
    __syncthreads();

    short8 af[4], bfr[4];
#pragma unroll
    for (int i = 0; i < 4; ++i)
      af[i] = *(const short8*)(&As[(wm + i * 16 + l15) * 32 + quad * 8]);
#pragma unroll
    for (int j = 0; j < 4; ++j)
      bfr[j] = *(const short8*)(&Bs[(wn + j * 16 + l15) * 32 + quad * 8]);
#pragma unroll
    for (int i = 0; i < 4; ++i)
#pragma unroll
      for (int j = 0; j < 4; ++j)
        acc[i][j] = __builtin_amdgcn_mfma_f32_16x16x32_bf16(af[i], bfr[j], acc[i][j], 0, 0, 0);
  }

#pragma unroll
  for (int i = 0; i < 4; ++i)
#pragma unroll
    for (int j = 0; j < 4; ++j)
#pragma unroll
      for (int r = 0; r < 4; ++r) {
        int row = m0 + wm + i * 16 + quad * 4 + r;
        int col = n0 + wn + j * 16 + l15;
        C[(size_t)row * Nda + col] = acc[i][j][r];
      }
}

// ---------------------------------------------------------------------------
// In-place RoPE on bf16 Q and K flat [M][1024].
// Q additionally pre-scaled by 1/sqrt(DHEAD)=0.125 (exact in bf16).
// ---------------------------------------------------------------------------
__global__ __launch_bounds__(256) void rope_inplace(unsigned short* __restrict__ Q,
                                                    unsigned short* __restrict__ K,
                                                    const int* __restrict__ pos_arr) {
  const int row = blockIdx.x;            // b*SEQ + s
  const int s = row & (SEQL - 1);
  const float pos = (float)pos_arr[s];
  // log2(10000)/32 = 0.4152410118609203
  for (int p = threadIdx.x; p < 512; p += 256) {
    const int h = p >> 5, i = p & 31;
    float inv = exp2f((float)i * -0.4152410118609203f);
    float ang = pos * inv;
    float sn, cs;
    sincosf(ang, &sn, &cs);
    size_t base = (size_t)row * DMODEL + h * DHEAD + 2 * i;
    float e = bf2f(Q[base]), o = bf2f(Q[base + 1]);
    Q[base]     = f2bf((e * cs - o * sn) * 0.125f);
    Q[base + 1] = f2bf((e * sn + o * cs) * 0.125f);
    e = bf2f(K[base]); o = bf2f(K[base + 1]);
    K[base]     = f2bf(e * cs - o * sn);
    K[base + 1] = f2bf(e * sn + o * cs);
  }
}

// ---------------------------------------------------------------------------
// Causal attention, R5-verified transposed-MFMA math + R10 single-barrier
// double-buffered DMA staging: preload tile 0; each trip syncs once (the
// barrier's vmcnt(0) drain waits on a DMA issued one full compute phase ago
// -> latency hidden), issues DMA for tile t+1 into the other buffer, then
// computes tile t. Buffer parity is trip-uniform; between consecutive
// barriers all waves are in the same trip, and DMA always targets the buffer
// nobody reads this trip — race-free with ONE barrier per trip (vs 2 in R8,
// which exposed a full L2 round-trip per trip: ~2200 cyc/trip measured).
// ---------------------------------------------------------------------------
__global__ __launch_bounds__(256) void attn_kernel(const unsigned short* __restrict__ Kf,
                                                   const unsigned short* __restrict__ Vt,
                                                   unsigned short* __restrict__ Qio) {
  __shared__ __attribute__((aligned(16))) unsigned short Ks[2][2048];  // dbuf, 256 slots x 16B
  __shared__ __attribute__((aligned(16))) unsigned short Vs[2][2048];

  const int id = blockIdx.x;
  const int bh = ((id >> 8) << 3) | (id & 7);   // grp*8 + xcd (L2 locality)
  const int qblk = 31 - ((id >> 3) & 31);       // heavy q-blocks first
  const int b = bh >> 4, h = bh & 15;
  const int w = threadIdx.x >> 6;
  const int lane = threadIdx.x & 63;
  const int l15 = lane & 15, quad = lane >> 4;
  const int qw = qblk * 64 + w * 16;
  const int qrow = qw + l15;                    // this lane's q index

  // Q B-frag: n=l15 (q), k=8*quad+j (d)
  const unsigned short* qp = Qio + ((size_t)(b * SEQL + qrow)) * DMODEL + h * DHEAD + quad * 8;
  const short8 bq0 = *(const short8*)(qp);
  const short8 bq1 = *(const short8*)(qp + 32);

  // staging source addresses (lane-permuted so LDS slot = read layout)
  const int g = (w << 6) | lane;
  const int ktau = g >> 7, kseg = (g >> 4) & 7, km = g & 15;
  const int kvl = 8 * (km >> 2) + (km & 3) + 4 * ktau;
  const unsigned short* kstage = Kf + ((size_t)(b * SEQL + kvl)) * DMODEL + h * DHEAD + kseg * 8;
  const int vdb = (g >> 6) & 3, vq = (g >> 4) & 3, vm = g & 15;
  const unsigned short* vstage = Vt + ((size_t)(bh * DHEAD + vdb * 16 + vm)) * SEQL + vq * 8;
  const int woff = (w << 6) * 8;   // wave's 64-slot window within a buffer

  // fragment read offsets (shorts): slot = l15 + 16*quad, +64-slot strides
  const int rs = (l15 + (quad << 4)) << 3;

  f32x4 oa0 = {0.f, 0.f, 0.f, 0.f}, oa1 = oa0, oa2 = oa0, oa3 = oa0;  // d-blocks
  float lp = 0.f;   // partial row sum for q=qrow (this lane's kv slice)

  const int trips = 2 * qblk + 2;

  // preload tile 0 into buffer 0
  gload_lds16(kstage, Ks[0] + woff);
  gload_lds16(vstage, Vs[0] + woff);

  for (int t = 0; t < trips; ++t) {
    __syncthreads();   // drains DMA(t) (issued one compute phase ago); all waves in same trip
    const int cur = t & 1;
    if (t + 1 < trips) {   // prefetch tile t+1 into the other buffer
      const int nkv = (t + 1) * 32;
      gload_lds16(kstage + (size_t)nkv * DMODEL, Ks[cur ^ 1] + woff);
      gload_lds16(vstage + nkv, Vs[cur ^ 1] + woff);
    }

    const unsigned short* ksb = Ks[cur];
    const unsigned short* vsb = Vs[cur];
    const short8 ak10 = *(const short8*)(ksb + rs);
    const short8 ak11 = *(const short8*)(ksb + rs + 512);
    const short8 ak20 = *(const short8*)(ksb + rs + 1024);
    const short8 ak21 = *(const short8*)(ksb + rs + 1536);
    f32x4 z = {0.f, 0.f, 0.f, 0.f};
    f32x4 s1 = __builtin_amdgcn_mfma_f32_16x16x32_bf16(ak10, bq0, z, 0, 0, 0);
    s1 = __builtin_amdgcn_mfma_f32_16x16x32_bf16(ak11, bq1, s1, 0, 0, 0);
    f32x4 s2 = __builtin_amdgcn_mfma_f32_16x16x32_bf16(ak20, bq0, z, 0, 0, 0);
    s2 = __builtin_amdgcn_mfma_f32_16x16x32_bf16(ak21, bq1, s2, 0, 0, 0);

    // exp + causal mask + pack into PV B-operand layout (kv = 8*quad + j)
    const int kv0 = t * 32;
    short8 bp;
#pragma unroll
    for (int r = 0; r < 4; ++r) {
      const int kv1 = kv0 + 8 * quad + r;
      const float p1 = (kv1 > qrow)     ? 0.f : __expf(s1[r]);
      const float p2 = (kv1 + 4 > qrow) ? 0.f : __expf(s2[r]);
      lp += p1 + p2;
      bp[r]     = (short)f2bf(p1);
      bp[4 + r] = (short)f2bf(p2);
    }

    const short8 av0 = *(const short8*)(vsb + rs);
    const short8 av1 = *(const short8*)(vsb + rs + 512);
    const short8 av2 = *(const short8*)(vsb + rs + 1024);
    const short8 av3 = *(const short8*)(vsb + rs + 1536);
    oa0 = __builtin_amdgcn_mfma_f32_16x16x32_bf16(av0, bp, oa0, 0, 0, 0);
    oa1 = __builtin_amdgcn_mfma_f32_16x16x32_bf16(av1, bp, oa1, 0, 0, 0);
    oa2 = __builtin_amdgcn_mfma_f32_16x16x32_bf16(av2, bp, oa2, 0, 0, 0);
    oa3 = __builtin_amdgcn_mfma_f32_16x16x32_bf16(av3, bp, oa3, 0, 0, 0);
  }

  // reduce row sum across the 4 quads holding this q's kv slices
  lp += __shfl_xor(lp, 16);
  lp += __shfl_xor(lp, 32);
  const float il = 1.f / lp;

  // O^T: lane holds q=l15's d = db*16 + 4*quad + r  -> 4x ushort4 stores
  unsigned short* ob = Qio + ((size_t)(b * SEQL + qrow)) * DMODEL + h * DHEAD + quad * 4;
  {
    ushort4 v;
    v.x = f2bf(oa0[0] * il); v.y = f2bf(oa0[1] * il);
    v.z = f2bf(oa0[2] * il); v.w = f2bf(oa0[3] * il);
    *(ushort4*)(ob) = v;
    v.x = f2bf(oa1[0] * il); v.y = f2bf(oa1[1] * il);
    v.z = f2bf(oa1[2] * il); v.w = f2bf(oa1[3] * il);
    *(ushort4*)(ob + 16) = v;
    v.x = f2bf(oa2[0] * il); v.y = f2bf(oa2[1] * il);
    v.z = f2bf(oa2[2] * il); v.w = f2bf(oa2[3] * il);
    *(ushort4*)(ob + 32) = v;
    v.x = f2bf(oa3[0] * il); v.y = f2bf(oa3[1] * il);
    v.z = f2bf(oa3[2] * il); v.w = f2bf(oa3[3] * il);
    *(ushort4*)(ob + 48) = v;
  }
}

// ---------------------------------------------------------------------------
extern "C" void kernel_launch(void* const* d_in, const int* in_sizes, int n_in,
                              void* d_out, int out_size, void* d_ws, size_t ws_size,
                              hipStream_t stream) {
  (void)in_sizes; (void)n_in; (void)out_size; (void)ws_size;
  const float* x  = (const float*)d_in[0];
  const int* tpos = (const int*)d_in[1];
  const float* Wq = (const float*)d_in[2];
  const float* Wk = (const float*)d_in[3];
  const float* Wv = (const float*)d_in[4];
  const float* Wo = (const float*)d_in[5];
  float* out      = (float*)d_out;

  char* ws = (char*)d_ws;
  const size_t MB = 1024 * 1024;
  unsigned short* Qf  = (unsigned short*)(ws);            // 8 MB
  unsigned short* Kf  = (unsigned short*)(ws + 8 * MB);   // 8 MB
  unsigned short* Vt  = (unsigned short*)(ws + 16 * MB);  // 8 MB
  unsigned short* xb  = (unsigned short*)(ws + 24 * MB);  // 8 MB
  unsigned short* wqb = (unsigned short*)(ws + 32 * MB);  // 2 MB
  unsigned short* wkb = (unsigned short*)(ws + 34 * MB);  // 2 MB
  unsigned short* wvb = (unsigned short*)(ws + 36 * MB);  // 2 MB
  unsigned short* wob = (unsigned short*)(ws + 38 * MB);  // 2 MB -> 40 MB total

  // one-shot fp32 -> bf16 conversion (x + 4 weights)
  cvt_bf16<<<dim3(512, 8), 256, 0, stream>>>(x, Wq, Wk, Wv, Wo, xb, wqb, wkb, wvb, wob);
  // Q,K,V projections (all-bf16, async staging; V written transposed)
  gemm_qkv<<<dim3(8, 32, 3), 256, 0, stream>>>(xb, wqb, wkb, wvb, Qf, Kf, Vt, MROWS, DMODEL, DMODEL);
  // RoPE in place on Q,K (Q pre-scaled by 0.125)
  rope_inplace<<<dim3(MROWS), 256, 0, stream>>>(Qf, Kf, tpos);
  // causal attention; output in place into Qf (bf16); XCD-swizzled 1-D grid
  attn_kernel<<<dim3(SEQL / 64 * NHEADS * 2), 256, 0, stream>>>(Kf, Vt, Qf);
  // output projection (bf16 A, bf16 W, fp32 out)
  gemm_out<<<dim3(8, 32, 1), 256, 0, stream>>>(Qf, wob, out, MROWS, DMODEL, DMODEL);
}

// Round 11
// 202.096 us; speedup vs baseline: 1.1125x; 1.1125x over previous
//
#include <hip/hip_runtime.h>
#include <cstdint>
#include <cstddef>

#define SEQL   2048
#define DMODEL 1024
#define NHEADS 16
#define DHEAD  64
#define MROWS  4096   // BATCH * SEQ

typedef __attribute__((ext_vector_type(8))) short short8;   // 8 bf16 (4 VGPRs)
typedef __attribute__((ext_vector_type(4))) float f32x4;    // MFMA 16x16 C/D

__device__ __forceinline__ unsigned short f2bf(float x) {
  unsigned int u = __float_as_uint(x);
  u += 0x7fffu + ((u >> 16) & 1u);   // round-to-nearest-even
  return (unsigned short)(u >> 16);
}
__device__ __forceinline__ float bf2f(unsigned short u) {
  return __uint_as_float(((unsigned int)u) << 16);
}
// load 8 contiguous fp32, round to 8 bf16
__device__ __forceinline__ short8 cvt8(const float* __restrict__ p) {
  const float4 lo = *(const float4*)p;
  const float4 hi = *(const float4*)(p + 4);
  short8 v;
  v[0] = (short)f2bf(lo.x); v[1] = (short)f2bf(lo.y);
  v[2] = (short)f2bf(lo.z); v[3] = (short)f2bf(lo.w);
  v[4] = (short)f2bf(hi.x); v[5] = (short)f2bf(hi.y);
  v[6] = (short)f2bf(hi.z); v[7] = (short)f2bf(hi.w);
  return v;
}
// async global->LDS, 16B per lane; lds base must be wave-uniform
__device__ __forceinline__ void gload_lds16(const unsigned short* g, unsigned short* l) {
  __builtin_amdgcn_global_load_lds(
      (const __attribute__((address_space(1))) unsigned int*)g,
      (__attribute__((address_space(3))) unsigned int*)l, 16, 0, 0);
}

// ---------------------------------------------------------------------------
// One-shot fp32 -> bf16 conversion of x and the four weight matrices.
// ---------------------------------------------------------------------------
__global__ __launch_bounds__(256) void cvt_bf16(
    const float* __restrict__ x,  const float* __restrict__ wq,
    const float* __restrict__ wk, const float* __restrict__ wv,
    const float* __restrict__ wo,
    unsigned short* __restrict__ xb,  unsigned short* __restrict__ wqb,
    unsigned short* __restrict__ wkb, unsigned short* __restrict__ wvb,
    unsigned short* __restrict__ wob) {
  const int y = blockIdx.y;
  const float* src; unsigned short* dst;
  if (y < 4)       { src = x + ((size_t)y << 20); dst = xb + ((size_t)y << 20); }
  else if (y == 4) { src = wq; dst = wqb; }
  else if (y == 5) { src = wk; dst = wkb; }
  else if (y == 6) { src = wv; dst = wvb; }
  else             { src = wo; dst = wob; }
  const size_t i = ((size_t)blockIdx.x * 256 + threadIdx.x) * 8;
  *(short8*)(dst + i) = cvt8(src + i);
}

// ---------------------------------------------------------------------------
// QKV projection, all-bf16, async staging (m97-style).
// z=0 -> Q bf16; z=1 -> K bf16; z=2 -> V transposed into Vt.
// ---------------------------------------------------------------------------
__global__ __launch_bounds__(256) void gemm_qkv(
    const unsigned short* __restrict__ A,
    const unsigned short* __restrict__ W0, const unsigned short* __restrict__ W1,
    const unsigned short* __restrict__ W2,
    unsigned short* __restrict__ C0, unsigned short* __restrict__ C1,
    unsigned short* __restrict__ Vt,
    int Mda, int Nda, int Kda) {
  const unsigned short* W;
  if (blockIdx.z == 0)      W = W0;
  else if (blockIdx.z == 1) W = W1;
  else                      W = W2;

  __shared__ __attribute__((aligned(16))) unsigned short As[128 * 32];
  __shared__ __attribute__((aligned(16))) unsigned short Bs[128 * 32];

  const int t = threadIdx.x;
  const int m0 = blockIdx.y * 128, n0 = blockIdx.x * 128;
  const int w = t >> 6, lane = t & 63;
  const int l15 = lane & 15, quad = lane >> 4;
  const int wm = (w >> 1) * 64, wn = (w & 1) * 64;

  const int r1 = t >> 2,         c1 = (t & 3) * 8;
  const int r2 = (t + 256) >> 2, c2 = (t & 3) * 8;
  unsigned short* asd1 = As + (size_t)(w << 6) * 8;
  unsigned short* asd2 = As + (size_t)(256 + (w << 6)) * 8;
  unsigned short* bsd1 = Bs + (size_t)(w << 6) * 8;
  unsigned short* bsd2 = Bs + (size_t)(256 + (w << 6)) * 8;

  f32x4 acc[4][4] = {};

  for (int k0 = 0; k0 < Kda; k0 += 32) {
    __syncthreads();
    gload_lds16(A + (size_t)(m0 + r1) * Kda + k0 + c1, asd1);
    gload_lds16(A + (size_t)(m0 + r2) * Kda + k0 + c2, asd2);
    gload_lds16(W + (size_t)(n0 + r1) * Kda + k0 + c1, bsd1);
    gload_lds16(W + (size_t)(n0 + r2) * Kda + k0 + c2, bsd2);
    __syncthreads();

    short8 af[4], bfr[4];
#pragma unroll
    for (int i = 0; i < 4; ++i)
      af[i] = *(const short8*)(&As[(wm + i * 16 + l15) * 32 + quad * 8]);
#pragma unroll
    for (int j = 0; j < 4; ++j)
      bfr[j] = *(const short8*)(&Bs[(wn + j * 16 + l15) * 32 + quad * 8]);
#pragma unroll
    for (int i = 0; i < 4; ++i)
#pragma unroll
      for (int j = 0; j < 4; ++j)
        acc[i][j] = __builtin_amdgcn_mfma_f32_16x16x32_bf16(af[i], bfr[j], acc[i][j], 0, 0, 0);
  }

  if (blockIdx.z != 2) {
    unsigned short* C = (blockIdx.z == 0) ? C0 : C1;
#pragma unroll
    for (int i = 0; i < 4; ++i)
#pragma unroll
      for (int j = 0; j < 4; ++j)
#pragma unroll
        for (int r = 0; r < 4; ++r) {
          int row = m0 + wm + i * 16 + quad * 4 + r;
          int col = n0 + wn + j * 16 + l15;
          C[(size_t)row * Nda + col] = f2bf(acc[i][j][r]);
        }
  } else {
    // V transposed write: 4 consecutive s-values per 8B store
#pragma unroll
    for (int i = 0; i < 4; ++i) {
      const int srow = m0 + wm + i * 16 + quad * 4;   // b*SEQL + s (s%4==0)
      const int bq = srow >> 11, s = srow & (SEQL - 1);
#pragma unroll
      for (int j = 0; j < 4; ++j) {
        const int col = n0 + wn + j * 16 + l15;       // h*64 + d
        ushort4 v;
        v.x = f2bf(acc[i][j][0]); v.y = f2bf(acc[i][j][1]);
        v.z = f2bf(acc[i][j][2]); v.w = f2bf(acc[i][j][3]);
        *(ushort4*)(Vt + ((size_t)(bq * DMODEL + col)) * SEQL + s) = v;
      }
    }
  }
}

// ---------------------------------------------------------------------------
// Output projection: A bf16 [M][K], W bf16 [N][K], C fp32 [M][N]
// ---------------------------------------------------------------------------
__global__ __launch_bounds__(256) void gemm_out(
    const unsigned short* __restrict__ A,
    const unsigned short* __restrict__ W,
    float* __restrict__ C,
    int Mda, int Nda, int Kda) {
  __shared__ __attribute__((aligned(16))) unsigned short As[128 * 32];
  __shared__ __attribute__((aligned(16))) unsigned short Bs[128 * 32];

  const int t = threadIdx.x;
  const int m0 = blockIdx.y * 128, n0 = blockIdx.x * 128;
  const int w = t >> 6, lane = t & 63;
  const int l15 = lane & 15, quad = lane >> 4;
  const int wm = (w >> 1) * 64, wn = (w & 1) * 64;

  const int r1 = t >> 2,         c1 = (t & 3) * 8;
  const int r2 = (t + 256) >> 2, c2 = (t & 3) * 8;
  unsigned short* asd1 = As + (size_t)(w << 6) * 8;
  unsigned short* asd2 = As + (size_t)(256 + (w << 6)) * 8;
  unsigned short* bsd1 = Bs + (size_t)(w << 6) * 8;
  unsigned short* bsd2 = Bs + (size_t)(256 + (w << 6)) * 8;

  f32x4 acc[4][4] = {};

  for (int k0 = 0; k0 < Kda; k0 += 32) {
    __syncthreads();
    gload_lds16(A + (size_t)(m0 + r1) * Kda + k0 + c1, asd1);
    gload_lds16(A + (size_t)(m0 + r2) * Kda + k0 + c2, asd2);
    gload_lds16(W + (size_t)(n0 + r1) * Kda + k0 + c1, bsd1);
    gload_lds16(W + (size_t)(n0 + r2) * Kda + k0 + c2, bsd2);
    __syncthreads();

    short8 af[4], bfr[4];
#pragma unroll
    for (int i = 0; i < 4; ++i)
      af[i] = *(const short8*)(&As[(wm + i * 16 + l15) * 32 + quad * 8]);
#pragma unroll
    for (int j = 0; j < 4; ++j)
      bfr[j] = *(const short8*)(&Bs[(wn + j * 16 + l15) * 32 + quad * 8]);
#pragma unroll
    for (int i = 0; i < 4; ++i)
#pragma unroll
      for (int j = 0; j < 4; ++j)
        acc[i][j] = __builtin_amdgcn_mfma_f32_16x16x32_bf16(af[i], bfr[j], acc[i][j], 0, 0, 0);
  }

#pragma unroll
  for (int i = 0; i < 4; ++i)
#pragma unroll
    for (int j = 0; j < 4; ++j)
#pragma unroll
      for (int r = 0; r < 4; ++r) {
        int row = m0 + wm + i * 16 + quad * 4 + r;
        int col = n0 + wn + j * 16 + l15;
        C[(size_t)row * Nda + col] = acc[i][j][r];
      }
}

// ---------------------------------------------------------------------------
// In-place RoPE on bf16 Q and K flat [M][1024].
// Q additionally pre-scaled by 1/sqrt(DHEAD)=0.125 (exact in bf16).
// ---------------------------------------------------------------------------
__global__ __launch_bounds__(256) void rope_inplace(unsigned short* __restrict__ Q,
                                                    unsigned short* __restrict__ K,
                                                    const int* __restrict__ pos_arr) {
  const int row = blockIdx.x;            // b*SEQ + s
  const int s = row & (SEQL - 1);
  const float pos = (float)pos_arr[s];
  // log2(10000)/32 = 0.4152410118609203
  for (int p = threadIdx.x; p < 512; p += 256) {
    const int h = p >> 5, i = p & 31;
    float inv = exp2f((float)i * -0.4152410118609203f);
    float ang = pos * inv;
    float sn, cs;
    sincosf(ang, &sn, &cs);
    size_t base = (size_t)row * DMODEL + h * DHEAD + 2 * i;
    float e = bf2f(Q[base]), o = bf2f(Q[base + 1]);
    Q[base]     = f2bf((e * cs - o * sn) * 0.125f);
    Q[base + 1] = f2bf((e * sn + o * cs) * 0.125f);
    e = bf2f(K[base]); o = bf2f(K[base + 1]);
    K[base]     = f2bf(e * cs - o * sn);
    K[base + 1] = f2bf(e * sn + o * cs);
  }
}

// ---------------------------------------------------------------------------
// Causal attention, R5-verified transposed-MFMA math, R8-proven 2-barrier
// DMA staging, + R11:
//  (a) kv-tile 64 (16 KB LDS/trip, 16 MFMA/wave/trip): halves trip count,
//      amortizing the fixed per-trip barrier/drain cost over 2x compute.
//  (b) light/heavy pairing: block handles qblk p then 31-p -> uniform 33
//      trips/block; 512 blocks = exactly 2 resident/CU, no ramp/tail.
//  (c) wave-uniform fast path for fully-unmasked trips (skips 16 cmp+sel).
// ---------------------------------------------------------------------------
__global__ __launch_bounds__(256, 2) void attn_kernel(const unsigned short* __restrict__ Kf,
                                                      const unsigned short* __restrict__ Vt,
                                                      unsigned short* __restrict__ Qio) {
  __shared__ __attribute__((aligned(16))) unsigned short Ks[4096];  // 8 KB: kv64 x d64
  __shared__ __attribute__((aligned(16))) unsigned short Vs[4096];  // 8 KB: d64 x kv64

  const int id = blockIdx.x;                    // id = grp*128 + qpair*8 + xcd
  const int bh = ((id >> 7) << 3) | (id & 7);   // grp*8 + xcd (L2 locality)
  const int qpair = (id >> 3) & 15;             // 0..15
  const int b = bh >> 4, h = bh & 15;
  const int w = threadIdx.x >> 6;
  const int lane = threadIdx.x & 63;
  const int l15 = lane & 15, quad = lane >> 4;

  // staging source addresses (lane-permuted so LDS slot = fragment layout)
  const int g = (w << 6) | lane;
  const int ktau = g >> 7, kseg = (g >> 4) & 7, km = g & 15;
  const int kvl = 8 * (km >> 2) + (km & 3) + 4 * ktau;
  const unsigned short* kstage = Kf + ((size_t)(b * SEQL + kvl)) * DMODEL + h * DHEAD + kseg * 8;
  const int vdb = (g >> 6) & 3, vq = (g >> 4) & 3, vm = g & 15;
  const unsigned short* vstage = Vt + ((size_t)(bh * DHEAD + vdb * 16 + vm)) * SEQL + vq * 8;
  unsigned short* kdst0 = Ks + (size_t)(w << 6) * 8;          // kv 0..31 half
  unsigned short* kdst1 = Ks + 2048 + (size_t)(w << 6) * 8;   // kv 32..63 half
  unsigned short* vdst0 = Vs + (size_t)(w << 6) * 8;
  unsigned short* vdst1 = Vs + 2048 + (size_t)(w << 6) * 8;

  // fragment read offset (shorts) within a 2048-short half
  const int rs = (l15 + (quad << 4)) << 3;

#pragma unroll 1
  for (int phase = 0; phase < 2; ++phase) {
    const int qblk = (phase == 0) ? qpair : 31 - qpair;
    const int qw = qblk * 64 + w * 16;
    const int qrow = qw + l15;

    // Q B-frag: n=l15 (q), k=8*quad+j (d)
    const unsigned short* qp = Qio + ((size_t)(b * SEQL + qrow)) * DMODEL + h * DHEAD + quad * 8;
    const short8 bq0 = *(const short8*)(qp);
    const short8 bq1 = *(const short8*)(qp + 32);

    f32x4 oa0 = {0.f, 0.f, 0.f, 0.f}, oa1 = oa0, oa2 = oa0, oa3 = oa0;
    float lp = 0.f;

    const int trips = qblk + 1;   // kv64 tiles; block-uniform
    for (int t = 0; t < trips; ++t) {
      const int kv0 = t * 64;
      __syncthreads();   // all waves done reading previous tile
      gload_lds16(kstage + (size_t)kv0 * DMODEL, kdst0);
      gload_lds16(kstage + (size_t)(kv0 + 32) * DMODEL, kdst1);
      gload_lds16(vstage + kv0, vdst0);
      gload_lds16(vstage + kv0 + 32, vdst1);
      __syncthreads();   // staged data visible

      // QK^T: 4 score accumulators (kv groups +0, +4, +32, +36)
      const short8 ak10 = *(const short8*)(Ks + rs);
      const short8 ak11 = *(const short8*)(Ks + rs + 512);
      const short8 ak20 = *(const short8*)(Ks + rs + 1024);
      const short8 ak21 = *(const short8*)(Ks + rs + 1536);
      const short8 ak30 = *(const short8*)(Ks + 2048 + rs);
      const short8 ak31 = *(const short8*)(Ks + 2048 + rs + 512);
      const short8 ak40 = *(const short8*)(Ks + 2048 + rs + 1024);
      const short8 ak41 = *(const short8*)(Ks + 2048 + rs + 1536);
      f32x4 z = {0.f, 0.f, 0.f, 0.f};
      f32x4 s1 = __builtin_amdgcn_mfma_f32_16x16x32_bf16(ak10, bq0, z, 0, 0, 0);
      s1 = __builtin_amdgcn_mfma_f32_16x16x32_bf16(ak11, bq1, s1, 0, 0, 0);
      f32x4 s2 = __builtin_amdgcn_mfma_f32_16x16x32_bf16(ak20, bq0, z, 0, 0, 0);
      s2 = __builtin_amdgcn_mfma_f32_16x16x32_bf16(ak21, bq1, s2, 0, 0, 0);
      f32x4 s3 = __builtin_amdgcn_mfma_f32_16x16x32_bf16(ak30, bq0, z, 0, 0, 0);
      s3 = __builtin_amdgcn_mfma_f32_16x16x32_bf16(ak31, bq1, s3, 0, 0, 0);
      f32x4 s4 = __builtin_amdgcn_mfma_f32_16x16x32_bf16(ak40, bq0, z, 0, 0, 0);
      s4 = __builtin_amdgcn_mfma_f32_16x16x32_bf16(ak41, bq1, s4, 0, 0, 0);

      // exp (+causal mask on the last trip per wave) -> PV B-operands
      short8 bp0, bp1;
      if (kv0 + 63 <= qw) {   // wave-uniform fast path: no masking needed
#pragma unroll
        for (int r = 0; r < 4; ++r) {
          const float p1 = __expf(s1[r]);
          const float p2 = __expf(s2[r]);
          const float p3 = __expf(s3[r]);
          const float p4 = __expf(s4[r]);
          lp += (p1 + p2) + (p3 + p4);
          bp0[r]     = (short)f2bf(p1);
          bp0[4 + r] = (short)f2bf(p2);
          bp1[r]     = (short)f2bf(p3);
          bp1[4 + r] = (short)f2bf(p4);
        }
      } else {
#pragma unroll
        for (int r = 0; r < 4; ++r) {
          const int kv1 = kv0 + 8 * quad + r;
          const float p1 = (kv1 > qrow)      ? 0.f : __expf(s1[r]);
          const float p2 = (kv1 + 4 > qrow)  ? 0.f : __expf(s2[r]);
          const float p3 = (kv1 + 32 > qrow) ? 0.f : __expf(s3[r]);
          const float p4 = (kv1 + 36 > qrow) ? 0.f : __expf(s4[r]);
          lp += (p1 + p2) + (p3 + p4);
          bp0[r]     = (short)f2bf(p1);
          bp0[4 + r] = (short)f2bf(p2);
          bp1[r]     = (short)f2bf(p3);
          bp1[4 + r] = (short)f2bf(p4);
        }
      }

      // PV: A = V^T frags (d-block x kv-half), B = bp
      const short8 av0l = *(const short8*)(Vs + rs);
      const short8 av1l = *(const short8*)(Vs + rs + 512);
      const short8 av2l = *(const short8*)(Vs + rs + 1024);
      const short8 av3l = *(const short8*)(Vs + rs + 1536);
      const short8 av0h = *(const short8*)(Vs + 2048 + rs);
      const short8 av1h = *(const short8*)(Vs + 2048 + rs + 512);
      const short8 av2h = *(const short8*)(Vs + 2048 + rs + 1024);
      const short8 av3h = *(const short8*)(Vs + 2048 + rs + 1536);
      oa0 = __builtin_amdgcn_mfma_f32_16x16x32_bf16(av0l, bp0, oa0, 0, 0, 0);
      oa1 = __builtin_amdgcn_mfma_f32_16x16x32_bf16(av1l, bp0, oa1, 0, 0, 0);
      oa2 = __builtin_amdgcn_mfma_f32_16x16x32_bf16(av2l, bp0, oa2, 0, 0, 0);
      oa3 = __builtin_amdgcn_mfma_f32_16x16x32_bf16(av3l, bp0, oa3, 0, 0, 0);
      oa0 = __builtin_amdgcn_mfma_f32_16x16x32_bf16(av0h, bp1, oa0, 0, 0, 0);
      oa1 = __builtin_amdgcn_mfma_f32_16x16x32_bf16(av1h, bp1, oa1, 0, 0, 0);
      oa2 = __builtin_amdgcn_mfma_f32_16x16x32_bf16(av2h, bp1, oa2, 0, 0, 0);
      oa3 = __builtin_amdgcn_mfma_f32_16x16x32_bf16(av3h, bp1, oa3, 0, 0, 0);
    }

    // reduce row sum across the 4 quads holding this q's kv slices
    lp += __shfl_xor(lp, 16);
    lp += __shfl_xor(lp, 32);
    const float il = 1.f / lp;

    // O^T: lane holds q=l15's d = db*16 + 4*quad + r  -> 4x ushort4 stores
    unsigned short* ob = Qio + ((size_t)(b * SEQL + qrow)) * DMODEL + h * DHEAD + quad * 4;
    {
      ushort4 v;
      v.x = f2bf(oa0[0] * il); v.y = f2bf(oa0[1] * il);
      v.z = f2bf(oa0[2] * il); v.w = f2bf(oa0[3] * il);
      *(ushort4*)(ob) = v;
      v.x = f2bf(oa1[0] * il); v.y = f2bf(oa1[1] * il);
      v.z = f2bf(oa1[2] * il); v.w = f2bf(oa1[3] * il);
      *(ushort4*)(ob + 16) = v;
      v.x = f2bf(oa2[0] * il); v.y = f2bf(oa2[1] * il);
      v.z = f2bf(oa2[2] * il); v.w = f2bf(oa2[3] * il);
      *(ushort4*)(ob + 32) = v;
      v.x = f2bf(oa3[0] * il); v.y = f2bf(oa3[1] * il);
      v.z = f2bf(oa3[2] * il); v.w = f2bf(oa3[3] * il);
      *(ushort4*)(ob + 48) = v;
    }
  }
}

// ---------------------------------------------------------------------------
extern "C" void kernel_launch(void* const* d_in, const int* in_sizes, int n_in,
                              void* d_out, int out_size, void* d_ws, size_t ws_size,
                              hipStream_t stream) {
  (void)in_sizes; (void)n_in; (void)out_size; (void)ws_size;
  const float* x  = (const float*)d_in[0];
  const int* tpos = (const int*)d_in[1];
  const float* Wq = (const float*)d_in[2];
  const float* Wk = (const float*)d_in[3];
  const float* Wv = (const float*)d_in[4];
  const float* Wo = (const float*)d_in[5];
  float* out      = (float*)d_out;

  char* ws = (char*)d_ws;
  const size_t MB = 1024 * 1024;
  unsigned short* Qf  = (unsigned short*)(ws);            // 8 MB
  unsigned short* Kf  = (unsigned short*)(ws + 8 * MB);   // 8 MB
  unsigned short* Vt  = (unsigned short*)(ws + 16 * MB);  // 8 MB
  unsigned short* xb  = (unsigned short*)(ws + 24 * MB);  // 8 MB
  unsigned short* wqb = (unsigned short*)(ws + 32 * MB);  // 2 MB
  unsigned short* wkb = (unsigned short*)(ws + 34 * MB);  // 2 MB
  unsigned short* wvb = (unsigned short*)(ws + 36 * MB);  // 2 MB
  unsigned short* wob = (unsigned short*)(ws + 38 * MB);  // 2 MB -> 40 MB total

  // one-shot fp32 -> bf16 conversion (x + 4 weights)
  cvt_bf16<<<dim3(512, 8), 256, 0, stream>>>(x, Wq, Wk, Wv, Wo, xb, wqb, wkb, wvb, wob);
  // Q,K,V projections (all-bf16, async staging; V written transposed)
  gemm_qkv<<<dim3(8, 32, 3), 256, 0, stream>>>(xb, wqb, wkb, wvb, Qf, Kf, Vt, MROWS, DMODEL, DMODEL);
  // RoPE in place on Q,K (Q pre-scaled by 0.125)
  rope_inplace<<<dim3(MROWS), 256, 0, stream>>>(Qf, Kf, tpos);
  // causal attention; 512 paired blocks (uniform 33 trips), XCD-swizzled
  attn_kernel<<<dim3(512), 256, 0, stream>>>(Kf, Vt, Qf);
  // output projection (bf16 A, bf16 W, fp32 out)
  gemm_out<<<dim3(8, 32, 1), 256, 0, stream>>>(Qf, wob, out, MROWS, DMODEL, DMODEL);
}